// Round 3
// baseline (790.201 us; speedup 1.0000x reference)
//
#include <hip/hip_runtime.h>
#include <math.h>

// Problem shape (fixed by reference): B=32, T=4096, H=1024, fp32.
#define B_    32
#define T_    4096
#define H_    1024
#define H4_   256            // float4 per (b,t) row
#define NC_   32             // t-chunks per b (both passes)
#define CH_   (T_ / NC_)     // 128 t per chunk
#define WPT_  (CH_ / 4)      // 32 t per wave (4 waves/block, pass 1)

// ---------------------------------------------------------------------------
// Design note (round 3): the previous single-eh-read flash kernel ran at
// ~1.6 TB/s regardless of sync structure (two totally different schedules,
// identical time) -> the limiter is its address pattern: every block reads
// 32 x 4 KiB rows at exactly 16 MiB stride, all blocks in lockstep.  The
// contiguous 2 GiB harness fill hits 6.4 TB/s on the same chip.  So we trade
// one extra eh read for contiguity: two streaming passes whose per-wave /
// per-block reads are long contiguous runs, no barriers in any inner loop,
// latency hidden by plain TLP (16 waves/CU).  Traffic ~1.03 GiB ~ 180 us.
// ---------------------------------------------------------------------------

// Pass 1: score partials. Grid B_*NC_=1024 blocks x 256 thr (4 waves).
// Block (b, c); wave w owns t in [c*128 + w*32, +32) and streams 32
// contiguous 4 KiB rows (128 KiB contiguous per wave). Per t: 4 float4
// loads/lane, dot with resident s-fragment, 6-level in-wave shfl reduce,
// lane 0 writes psc[t*B_+b]. No block barriers at all.
__global__ __launch_bounds__(256) void score_kernel(
    const float4* __restrict__ s4, const float4* __restrict__ eh4,
    float* __restrict__ psc)
{
    const int blk  = blockIdx.x;
    const int b    = blk >> 5;          // 0..31
    const int c    = blk & 31;          // 0..31
    const int tid  = threadIdx.x;
    const int lane = tid & 63;
    const int w    = tid >> 6;          // wave 0..3

    float4 sreg[4];
#pragma unroll
    for (int j = 0; j < 4; ++j)
        sreg[j] = s4[b * H4_ + lane + 64 * j];

    const int tbase = c * CH_ + w * WPT_;
    const float4* rowp = eh4 + ((size_t)b * T_ + tbase) * H4_ + lane;

    // 1-ahead prefetch: next row's loads are in flight during the reduce.
    float4 c0 = rowp[0], c1 = rowp[64], c2 = rowp[128], c3 = rowp[192];

    for (int i = 0; i < WPT_; ++i) {
        float4 n0, n1, n2, n3;
        if (i < WPT_ - 1) {
            rowp += H4_;
            n0 = rowp[0]; n1 = rowp[64]; n2 = rowp[128]; n3 = rowp[192];
        }

        float p = c0.x * sreg[0].x + c0.y * sreg[0].y
                + c0.z * sreg[0].z + c0.w * sreg[0].w
                + c1.x * sreg[1].x + c1.y * sreg[1].y
                + c1.z * sreg[1].z + c1.w * sreg[1].w
                + c2.x * sreg[2].x + c2.y * sreg[2].y
                + c2.z * sreg[2].z + c2.w * sreg[2].w
                + c3.x * sreg[3].x + c3.y * sreg[3].y
                + c3.z * sreg[3].z + c3.w * sreg[3].w;
        for (int off = 32; off > 0; off >>= 1)
            p += __shfl_down(p, off, 64);
        if (lane == 0) psc[(size_t)(tbase + i) * B_ + b] = p;

        if (i < WPT_ - 1) { c0 = n0; c1 = n1; c2 = n2; c3 = n3; }
    }
}

// Pass 1.5: fold b, global softmax -> weights w[4096]. One block, 1024 thr.
// psc is 512 KiB (L2-hot). Thread handles t in {tid, tid+1024, ...}: each
// reads 32 contiguous floats (layout [t][b]) -> block reads are contiguous.
__global__ __launch_bounds__(1024) void softmax_kernel(
    const float* __restrict__ psc, float* __restrict__ wout)
{
    const int tid  = threadIdx.x;
    const int lane = tid & 63;
    const int w    = tid >> 6;
    __shared__ float red[16];

    float s[4];
#pragma unroll
    for (int k = 0; k < 4; ++k) {
        const float4* pp = (const float4*)psc + (size_t)(tid + 1024 * k) * 8;
        float acc = 0.f;
#pragma unroll
        for (int j = 0; j < 8; ++j) {
            float4 a = pp[j];
            acc += (a.x + a.y) + (a.z + a.w);
        }
        s[k] = acc;
    }

    // global max
    float M = fmaxf(fmaxf(s[0], s[1]), fmaxf(s[2], s[3]));
    for (int off = 32; off > 0; off >>= 1)
        M = fmaxf(M, __shfl_down(M, off, 64));
    if (lane == 0) red[w] = M;
    __syncthreads();
    float Mg = -INFINITY;
#pragma unroll
    for (int j = 0; j < 16; ++j) Mg = fmaxf(Mg, red[j]);
    __syncthreads();

    // global sum of exps
    float e[4];
    float ls = 0.f;
#pragma unroll
    for (int k = 0; k < 4; ++k) { e[k] = __expf(s[k] - Mg); ls += e[k]; }
    for (int off = 32; off > 0; off >>= 1)
        ls += __shfl_down(ls, off, 64);
    if (lane == 0) red[w] = ls;
    __syncthreads();
    float Lg = 0.f;
#pragma unroll
    for (int j = 0; j < 16; ++j) Lg += red[j];
    const float inv = 1.f / Lg;

#pragma unroll
    for (int k = 0; k < 4; ++k) wout[tid + 1024 * k] = e[k] * inv;
}

// Pass 2: context partials. Grid B_*NC_=1024 blocks x 256 thr. Block (b,c)
// streams its 512 KiB chunk contiguously (4 KiB per t-iteration across the
// block), thread owns one float4 of the output row. Weights broadcast from
// LDS. Partial out op4[b][c][h4] (4 MiB).
__global__ __launch_bounds__(256) void ctx_kernel(
    const float4* __restrict__ eh4, const float* __restrict__ wv,
    float4* __restrict__ op4)
{
    const int blk = blockIdx.x;
    const int b   = blk >> 5;
    const int c   = blk & 31;
    const int tid = threadIdx.x;

    __shared__ float wl[CH_];
    if (tid < CH_) wl[tid] = wv[c * CH_ + tid];
    __syncthreads();

    const float4* p = eh4 + ((size_t)b * T_ + c * CH_) * H4_ + tid;
    float4 acc = make_float4(0.f, 0.f, 0.f, 0.f);
#pragma unroll 8
    for (int t = 0; t < CH_; ++t) {
        float4 a = p[(size_t)t * H4_];
        const float ww = wl[t];
        acc.x += ww * a.x; acc.y += ww * a.y;
        acc.z += ww * a.z; acc.w += ww * a.w;
    }
    op4[((size_t)b * NC_ + c) * H4_ + tid] = acc;
}

// Pass 2b: fold the 32 chunk partials per output element. 32 blocks x 256.
__global__ __launch_bounds__(256) void comb_kernel(
    const float4* __restrict__ op4, float4* __restrict__ out4)
{
    const int o4 = blockIdx.x * 256 + threadIdx.x;
    const int b  = o4 >> 8;
    const int h4 = o4 & 255;
    const float4* p = op4 + (size_t)b * NC_ * H4_ + h4;
    float4 acc = make_float4(0.f, 0.f, 0.f, 0.f);
#pragma unroll 8
    for (int c = 0; c < NC_; ++c) {
        float4 a = p[(size_t)c * H4_];
        acc.x += a.x; acc.y += a.y; acc.z += a.z; acc.w += a.w;
    }
    out4[o4] = acc;
}

extern "C" void kernel_launch(void* const* d_in, const int* in_sizes, int n_in,
                              void* d_out, int out_size, void* d_ws, size_t ws_size,
                              hipStream_t stream) {
    const float* s  = (const float*)d_in[0];   // [B, H]
    const float* eh = (const float*)d_in[1];   // [B, T, H]

    float* psc = (float*)d_ws;                         // T_*B_ = 512 KiB
    float* wv  = psc + (size_t)T_ * B_;                // T_ floats = 16 KiB
    float4* op = (float4*)((char*)d_ws + (1 << 20));   // B_*NC_*H4_ f4 = 4 MiB

    score_kernel<<<B_ * NC_, 256, 0, stream>>>(
        (const float4*)s, (const float4*)eh, psc);
    softmax_kernel<<<1, 1024, 0, stream>>>(psc, wv);
    ctx_kernel<<<B_ * NC_, 256, 0, stream>>>((const float4*)eh, wv, op);
    comb_kernel<<<(B_ * H4_) / 256, 256, 0, stream>>>(op, (float4*)d_out);
}